// Round 1
// baseline (8540.851 us; speedup 1.0000x reference)
//
#include <hip/hip_runtime.h>
#include <cstdint>

#define D 128

// ---------------------------------------------------------------------------
// Scatter: acc[row] += val * h_all[col]   (h_all = concat(h_item, h_user))
// 32 threads per edge, one float4 each -> 4 f32 atomics per thread.
// ---------------------------------------------------------------------------
__global__ __launch_bounds__(256) void scatter_kernel(
    const float* __restrict__ h_item, const float* __restrict__ h_user,
    const float* __restrict__ vals, const int* __restrict__ rows,
    const int* __restrict__ cols, float* __restrict__ acc, int E, int Ni)
{
    int idx = blockIdx.x * 256 + threadIdx.x;
    int total = E * 32;
    if (idx >= total) return;
    int e = idx >> 5;
    int q = (idx & 31) * 4;   // float offset within the 128-wide row

    int row = rows[e];
    int col = cols[e];
    float v = vals[e];
    const float* src = (col < Ni) ? (h_item + (size_t)col * D)
                                  : (h_user + (size_t)(col - Ni) * D);
    float4 x = *reinterpret_cast<const float4*>(src + q);
    float* dst = acc + (size_t)row * D + q;
    atomicAdd(dst + 0, v * x.x);
    atomicAdd(dst + 1, v * x.y);
    atomicAdd(dst + 2, v * x.z);
    atomicAdd(dst + 3, v * x.w);
}

// ---------------------------------------------------------------------------
// GEMM: C[m][n] (+)= sum_k (A[m][k] (+ H[m][k])) * W[n][k]
// optional bias + relu epilogue. Tile 64 rows x 64 cols, 256 threads,
// 4x4 micro-tile per thread. K = N = 128 fixed.
// LDS: At[k][m], Wt[k][n] with stride 68 (aligned float4, conflict-free).
// ---------------------------------------------------------------------------
template<bool ACCUM, bool ADD_H, bool BIAS_RELU>
__global__ __launch_bounds__(256) void gemm_wt(
    const float* __restrict__ A, const float* __restrict__ H,
    const float* __restrict__ W, const float* __restrict__ bias,
    float* __restrict__ C, int M)
{
    __shared__ float At[128 * 68];
    __shared__ float Wt[128 * 68];
    const int tid = threadIdx.x;
    const int row0 = blockIdx.x * 64;
    const int col0 = blockIdx.y * 64;

    // stage W rows [col0, col0+64) transposed: Wt[k][nl] = W[col0+nl][k]
    // consecutive threads: k consecutive -> LDS bank = (k*68+nl)%32 = (k*4+nl)%32
    // wait: scalar path below uses stride 68 -> bank (k*68+nl)%32; k consecutive
    // over a wave with fixed nl -> banks walk 68%32=4 apart? No: t = nl*128+k,
    // so for 128 consecutive t, nl fixed, k=0..127 -> addr k*68+nl -> bank
    // (k*68+nl)%32 = (4k+nl)%32 -> 8 distinct banks, 8-way on a one-time store. OK.
    for (int t = tid; t < 64 * 128; t += 256) {
        int nl = t >> 7, k = t & 127;
        Wt[k * 68 + nl] = W[(size_t)(col0 + nl) * 128 + k];
    }
    // stage A rows [row0, row0+64) transposed, with optional +H and M-guard
    for (int t = tid; t < 64 * 128; t += 256) {
        int m = t >> 7, k = t & 127;
        int gr = row0 + m;
        float a = 0.f;
        if (gr < M) {
            a = A[(size_t)gr * 128 + k];
            if constexpr (ADD_H) a += H[(size_t)gr * 128 + k];
        }
        At[k * 68 + m] = a;
    }
    __syncthreads();

    const int tx = tid & 15;   // -> cols col0 + tx*4 .. +3
    const int ty = tid >> 4;   // -> rows row0 + ty*4 .. +3
    float acc[4][4] = {};

    #pragma unroll 4
    for (int k = 0; k < 128; ++k) {
        float4 av = *reinterpret_cast<const float4*>(&At[k * 68 + ty * 4]);
        float4 wv = *reinterpret_cast<const float4*>(&Wt[k * 68 + tx * 4]);
        float a[4] = {av.x, av.y, av.z, av.w};
        float w[4] = {wv.x, wv.y, wv.z, wv.w};
        #pragma unroll
        for (int i = 0; i < 4; ++i)
            #pragma unroll
            for (int j = 0; j < 4; ++j)
                acc[i][j] = fmaf(a[i], w[j], acc[i][j]);
    }

    #pragma unroll
    for (int i = 0; i < 4; ++i) {
        int gr = row0 + ty * 4 + i;
        if (gr >= M) break;
        float4 r = make_float4(acc[i][0], acc[i][1], acc[i][2], acc[i][3]);
        float* cp = C + (size_t)gr * 128 + col0 + tx * 4;
        if constexpr (ACCUM) {
            float4 old = *reinterpret_cast<const float4*>(cp);
            r.x += old.x; r.y += old.y; r.z += old.z; r.w += old.w;
        }
        if constexpr (BIAS_RELU) {
            const float* bp = bias + col0 + tx * 4;
            r.x = fmaxf(r.x + bp[0], 0.f);
            r.y = fmaxf(r.y + bp[1], 0.f);
            r.z = fmaxf(r.z + bp[2], 0.f);
            r.w = fmaxf(r.w + bp[3], 0.f);
        }
        *reinterpret_cast<float4*>(cp) = r;
    }
}

// ---------------------------------------------------------------------------
extern "C" void kernel_launch(void* const* d_in, const int* in_sizes, int n_in,
                              void* d_out, int out_size, void* d_ws, size_t ws_size,
                              hipStream_t stream)
{
    const float* h_item = (const float*)d_in[0];
    const float* h_user = (const float*)d_in[1];
    const float* W_rel  = (const float*)d_in[2];
    const float* W_item = (const float*)d_in[3];
    const float* b_item = (const float*)d_in[4];
    const float* W_user = (const float*)d_in[5];
    const float* b_user = (const float*)d_in[6];
    const float* vals   = (const float*)d_in[7];
    const int*   rows   = (const int*)d_in[8];
    const int*   cols   = (const int*)d_in[9];

    const int Ni = in_sizes[0] / D;          // 80000
    const int Nu = in_sizes[1] / D;          // 20000
    const int N  = Ni + Nu;                  // 100000
    const int NR = in_sizes[2] / (D * D);    // 3
    const int E  = in_sizes[7] / NR;         // 1,600,000

    float* acc = (float*)d_ws;               // [N, 128] f32  (51.2 MB)
    float* msg = acc + (size_t)N * D;        // [N, 128] f32  (51.2 MB)
    float* out = (float*)d_out;

    hipMemsetAsync(msg, 0, (size_t)N * D * sizeof(float), stream);

    const int scatter_blocks = (E * 32 + 255) / 256;
    for (int r = 0; r < NR; ++r) {
        hipMemsetAsync(acc, 0, (size_t)N * D * sizeof(float), stream);
        scatter_kernel<<<scatter_blocks, 256, 0, stream>>>(
            h_item, h_user,
            vals + (size_t)r * E, rows + (size_t)r * E, cols + (size_t)r * E,
            acc, E, Ni);
        dim3 g((N + 63) / 64, 2);
        gemm_wt<true, false, false><<<g, 256, 0, stream>>>(
            acc, nullptr, W_rel + (size_t)r * D * D, nullptr, msg, N);
    }

    dim3 gi((Ni + 63) / 64, 2);
    gemm_wt<false, true, true><<<gi, 256, 0, stream>>>(
        msg, h_item, W_item, b_item, out, Ni);
    dim3 gu((Nu + 63) / 64, 2);
    gemm_wt<false, true, true><<<gu, 256, 0, stream>>>(
        msg + (size_t)Ni * D, h_user, W_user, b_user, out + (size_t)Ni * D, Nu);
}

// Round 2
// 1480.678 us; speedup vs baseline: 5.7682x; 5.7682x over previous
//
#include <hip/hip_runtime.h>
#include <cstdint>

#define D 128

__device__ __forceinline__ float bf2f(unsigned short u) {
    unsigned v = ((unsigned)u) << 16; float f; __builtin_memcpy(&f, &v, 4); return f;
}
__device__ __forceinline__ unsigned short f2bf(float f) {
    unsigned v; __builtin_memcpy(&v, &f, 4);
    v = v + 0x7FFFu + ((v >> 16) & 1u);      // round-to-nearest-even
    return (unsigned short)(v >> 16);
}

// ---------------------------------------------------------------------------
// 1. histogram of destination rows
// ---------------------------------------------------------------------------
__global__ __launch_bounds__(256) void hist_kernel(
    const int* __restrict__ rows, int* __restrict__ count, int E)
{
    int e = blockIdx.x * 256 + threadIdx.x;
    if (e < E) atomicAdd(&count[rows[e]], 1);
}

// ---------------------------------------------------------------------------
// 2. exclusive scan over N counters (3 kernels)
// ---------------------------------------------------------------------------
__global__ __launch_bounds__(256) void scan1_kernel(
    const int* __restrict__ count, int* __restrict__ offs,
    int* __restrict__ bsum, int n)
{
    int i = blockIdx.x * 256 + threadIdx.x;
    int lane = threadIdx.x & 63;
    int x = (i < n) ? count[i] : 0;
    int orig = x;
    #pragma unroll
    for (int d = 1; d < 64; d <<= 1) {
        int y = __shfl_up(x, d);
        if (lane >= d) x += y;
    }
    __shared__ int ws[4];
    int w = threadIdx.x >> 6;
    if (lane == 63) ws[w] = x;
    __syncthreads();
    int add = 0;
    for (int j = 0; j < w; ++j) add += ws[j];
    x += add;
    if (i < n) offs[i] = x - orig;               // exclusive (local)
    if (threadIdx.x == 255) bsum[blockIdx.x] = x; // block total
}

__global__ __launch_bounds__(64) void scan2_kernel(int* __restrict__ bsum, int nb)
{
    int lane = threadIdx.x;
    int carry = 0;
    for (int base = 0; base < nb; base += 64) {
        int i = base + lane;
        int x = (i < nb) ? bsum[i] : 0;
        int orig = x;
        #pragma unroll
        for (int d = 1; d < 64; d <<= 1) {
            int y = __shfl_up(x, d);
            if (lane >= d) x += y;
        }
        if (i < nb) bsum[i] = carry + x - orig;  // exclusive (global)
        carry += __shfl(x, 63);
    }
}

__global__ __launch_bounds__(256) void scan3_kernel(
    int* __restrict__ offs, int* __restrict__ cursor,
    const int* __restrict__ bsum, int n, int total)
{
    int i = blockIdx.x * 256 + threadIdx.x;
    if (i < n) {
        int v = offs[i] + bsum[blockIdx.x];
        offs[i] = v;
        cursor[i] = v;
    }
    if (i == 0) offs[n] = total;
}

// ---------------------------------------------------------------------------
// 3. place edges into row-sorted arrays
// ---------------------------------------------------------------------------
__global__ __launch_bounds__(256) void place_kernel(
    const int* __restrict__ rows, const int* __restrict__ cols,
    const float* __restrict__ vals, int* __restrict__ cursor,
    int* __restrict__ scol, float* __restrict__ sval, int E)
{
    int e = blockIdx.x * 256 + threadIdx.x;
    if (e >= E) return;
    int pos = atomicAdd(&cursor[rows[e]], 1);
    scol[pos] = cols[e];
    sval[pos] = vals[e];
}

// ---------------------------------------------------------------------------
// 4. per-row gather-accumulate: msg[row] (=/+=) sum_edges val * hr[col]
//    one wave per row; lane holds features (2*lane, 2*lane+1)
// ---------------------------------------------------------------------------
__global__ __launch_bounds__(256) void accum_kernel(
    const unsigned short* __restrict__ hr, const int* __restrict__ offs,
    const int* __restrict__ scol, const float* __restrict__ sval,
    float* __restrict__ msg, int N, int first)
{
    int row = blockIdx.x * 4 + (threadIdx.x >> 6);
    if (row >= N) return;
    int lane = threadIdx.x & 63;
    int s = offs[row], t = offs[row + 1];
    float a0 = 0.f, a1 = 0.f;
    for (int p = s; p < t; ++p) {
        int c = scol[p];
        float v = sval[p];
        ushort2 u = *reinterpret_cast<const ushort2*>(hr + (size_t)c * D + lane * 2);
        a0 = fmaf(v, bf2f(u.x), a0);
        a1 = fmaf(v, bf2f(u.y), a1);
    }
    float2* mp = reinterpret_cast<float2*>(msg + (size_t)row * D + lane * 2);
    if (first) {
        *mp = make_float2(a0, a1);
    } else {
        float2 o = *mp;
        *mp = make_float2(o.x + a0, o.y + a1);
    }
}

// ---------------------------------------------------------------------------
// GEMM: C[m][n] = (A[m][k] (+ H[m][k])) * W[n][k], K = Ncol = 128.
// CONCAT: A is concat(A, A2) split at row Ni. OUTBF16: C stored bf16.
// Tile 64x64, 256 threads, 4x4 micro-tile. LDS transposed, stride 68.
// ---------------------------------------------------------------------------
template<bool CONCAT, bool OUTBF16, bool ADD_H, bool BIAS_RELU>
__global__ __launch_bounds__(256) void gemm_wt(
    const float* __restrict__ A, const float* __restrict__ A2,
    const float* __restrict__ H, const float* __restrict__ W,
    const float* __restrict__ bias, void* __restrict__ Cout,
    int M, int Ni)
{
    __shared__ float At[128 * 68];
    __shared__ float Wt[128 * 68];
    const int tid = threadIdx.x;
    const int row0 = blockIdx.x * 64;
    const int col0 = blockIdx.y * 64;

    for (int t = tid; t < 64 * 128; t += 256) {
        int nl = t >> 7, k = t & 127;
        Wt[k * 68 + nl] = W[(size_t)(col0 + nl) * D + k];
    }
    for (int t = tid; t < 64 * 128; t += 256) {
        int m = t >> 7, k = t & 127;
        int gr = row0 + m;
        float a = 0.f;
        if (gr < M) {
            if constexpr (CONCAT) {
                const float* src = (gr < Ni) ? A + (size_t)gr * D
                                             : A2 + (size_t)(gr - Ni) * D;
                a = src[k];
            } else {
                a = A[(size_t)gr * D + k];
                if constexpr (ADD_H) a += H[(size_t)gr * D + k];
            }
        }
        At[k * 68 + m] = a;
    }
    __syncthreads();

    const int tx = tid & 15;
    const int ty = tid >> 4;
    float acc[4][4] = {};

    #pragma unroll 4
    for (int k = 0; k < 128; ++k) {
        float4 av = *reinterpret_cast<const float4*>(&At[k * 68 + ty * 4]);
        float4 wv = *reinterpret_cast<const float4*>(&Wt[k * 68 + tx * 4]);
        float a[4] = {av.x, av.y, av.z, av.w};
        float w[4] = {wv.x, wv.y, wv.z, wv.w};
        #pragma unroll
        for (int i = 0; i < 4; ++i)
            #pragma unroll
            for (int j = 0; j < 4; ++j)
                acc[i][j] = fmaf(a[i], w[j], acc[i][j]);
    }

    #pragma unroll
    for (int i = 0; i < 4; ++i) {
        int gr = row0 + ty * 4 + i;
        if (gr >= M) break;
        if constexpr (OUTBF16) {
            ushort4 r4;
            r4.x = f2bf(acc[i][0]); r4.y = f2bf(acc[i][1]);
            r4.z = f2bf(acc[i][2]); r4.w = f2bf(acc[i][3]);
            *reinterpret_cast<ushort4*>(
                (unsigned short*)Cout + (size_t)gr * D + col0 + tx * 4) = r4;
        } else {
            float4 r = make_float4(acc[i][0], acc[i][1], acc[i][2], acc[i][3]);
            if constexpr (BIAS_RELU) {
                const float* bp = bias + col0 + tx * 4;
                r.x = fmaxf(r.x + bp[0], 0.f);
                r.y = fmaxf(r.y + bp[1], 0.f);
                r.z = fmaxf(r.z + bp[2], 0.f);
                r.w = fmaxf(r.w + bp[3], 0.f);
            }
            *reinterpret_cast<float4*>((float*)Cout + (size_t)gr * D + col0 + tx * 4) = r;
        }
    }
}

// ---------------------------------------------------------------------------
extern "C" void kernel_launch(void* const* d_in, const int* in_sizes, int n_in,
                              void* d_out, int out_size, void* d_ws, size_t ws_size,
                              hipStream_t stream)
{
    const float* h_item = (const float*)d_in[0];
    const float* h_user = (const float*)d_in[1];
    const float* W_rel  = (const float*)d_in[2];
    const float* W_item = (const float*)d_in[3];
    const float* b_item = (const float*)d_in[4];
    const float* W_user = (const float*)d_in[5];
    const float* b_user = (const float*)d_in[6];
    const float* vals   = (const float*)d_in[7];
    const int*   rows   = (const int*)d_in[8];
    const int*   cols   = (const int*)d_in[9];

    const int Ni = in_sizes[0] / D;          // 80000
    const int Nu = in_sizes[1] / D;          // 20000
    const int N  = Ni + Nu;                  // 100000
    const int NR = in_sizes[2] / (D * D);    // 3
    const int E  = in_sizes[7] / NR;         // 1,600,000

    // workspace carve (~91 MB total)
    char* p = (char*)d_ws;
    float* msg = (float*)p;            p += (size_t)N * D * sizeof(float);   // 51.2 MB
    unsigned short* hr = (unsigned short*)p; p += (size_t)N * D * 2;         // 25.6 MB
    int*   scol = (int*)p;             p += (size_t)E * sizeof(int);         // 6.4 MB
    float* sval = (float*)p;           p += (size_t)E * sizeof(float);       // 6.4 MB
    int*   count = (int*)p;            p += (size_t)N * sizeof(int);
    int*   offs  = (int*)p;            p += (size_t)(N + 1) * sizeof(int);
    int*   cursor = (int*)p;           p += (size_t)N * sizeof(int);
    int*   bsum  = (int*)p;            p += 4096;
    float* out = (float*)d_out;

    const int nb  = (N + 255) / 256;     // scan blocks
    const int ebk = (E + 255) / 256;     // edge blocks

    for (int r = 0; r < NR; ++r) {
        const int*   rr = rows + (size_t)r * E;
        const int*   cc = cols + (size_t)r * E;
        const float* vv = vals + (size_t)r * E;

        hipMemsetAsync(count, 0, (size_t)N * sizeof(int), stream);
        hist_kernel<<<ebk, 256, 0, stream>>>(rr, count, E);
        scan1_kernel<<<nb, 256, 0, stream>>>(count, offs, bsum, N);
        scan2_kernel<<<1, 64, 0, stream>>>(bsum, nb);
        scan3_kernel<<<nb, 256, 0, stream>>>(offs, cursor, bsum, N, E);
        place_kernel<<<ebk, 256, 0, stream>>>(rr, cc, vv, cursor, scol, sval, E);

        gemm_wt<true, true, false, false><<<dim3((N + 63) / 64, 2), 256, 0, stream>>>(
            h_item, h_user, nullptr, W_rel + (size_t)r * D * D, nullptr, hr, N, Ni);

        accum_kernel<<<(N + 3) / 4, 256, 0, stream>>>(
            hr, offs, scol, sval, msg, N, r == 0 ? 1 : 0);
    }

    gemm_wt<false, false, true, true><<<dim3((Ni + 63) / 64, 2), 256, 0, stream>>>(
        msg, nullptr, h_item, W_item, b_item, out, Ni, 0);
    gemm_wt<false, false, true, true><<<dim3((Nu + 63) / 64, 2), 256, 0, stream>>>(
        msg + (size_t)Ni * D, nullptr, h_user, W_user, b_user,
        out + (size_t)Ni * D, Nu, 0);
}

// Round 3
// 1099.119 us; speedup vs baseline: 7.7706x; 1.3472x over previous
//
#include <hip/hip_runtime.h>
#include <cstdint>

#define D 128

typedef short   bf8_t    __attribute__((ext_vector_type(8)));   // 8 bf16 (4 VGPR)
typedef float   f4_t     __attribute__((ext_vector_type(4)));
typedef unsigned short u8x16_t __attribute__((ext_vector_type(8))); // 8 x u16

__device__ __forceinline__ float bf2f(unsigned short u) {
    unsigned v = ((unsigned)u) << 16; float f; __builtin_memcpy(&f, &v, 4); return f;
}
__device__ __forceinline__ unsigned short f2bf(float f) {
    unsigned v; __builtin_memcpy(&v, &f, 4);
    v = v + 0x7FFFu + ((v >> 16) & 1u);      // round-to-nearest-even
    return (unsigned short)(v >> 16);
}

// ---------------------------------------------------------------------------
// 1. histogram of destination rows, all 3 relations in one pass
// ---------------------------------------------------------------------------
__global__ __launch_bounds__(256) void hist_all_kernel(
    const int* __restrict__ rows, int* __restrict__ count3, int E, int N)
{
    int idx = blockIdx.x * 256 + threadIdx.x;
    if (idx >= 3 * E) return;
    int rel = (idx >= 2 * E) ? 2 : (idx >= E ? 1 : 0);
    atomicAdd(&count3[rel * N + rows[idx]], 1);
}

// ---------------------------------------------------------------------------
// 2. exclusive scan per relation (grid.y / blockIdx.x = relation)
// ---------------------------------------------------------------------------
__global__ __launch_bounds__(256) void scan1_kernel(
    const int* __restrict__ count3, int* __restrict__ offs3,
    int* __restrict__ bsum3, int n)
{
    int rel = blockIdx.y;
    const int* count = count3 + (size_t)rel * n;
    int* offs = offs3 + (size_t)rel * (n + 1);
    int* bsum = bsum3 + (size_t)rel * 512;

    int i = blockIdx.x * 256 + threadIdx.x;
    int lane = threadIdx.x & 63;
    int x = (i < n) ? count[i] : 0;
    int orig = x;
    #pragma unroll
    for (int d = 1; d < 64; d <<= 1) {
        int y = __shfl_up(x, d);
        if (lane >= d) x += y;
    }
    __shared__ int ws[4];
    int w = threadIdx.x >> 6;
    if (lane == 63) ws[w] = x;
    __syncthreads();
    int add = 0;
    for (int j = 0; j < w; ++j) add += ws[j];
    x += add;
    if (i < n) offs[i] = x - orig;
    if (threadIdx.x == 255) bsum[blockIdx.x] = x;
}

__global__ __launch_bounds__(64) void scan2_kernel(int* __restrict__ bsum3, int nb)
{
    int* bsum = bsum3 + (size_t)blockIdx.x * 512;
    int lane = threadIdx.x;
    int carry = 0;
    for (int base = 0; base < nb; base += 64) {
        int i = base + lane;
        int x = (i < nb) ? bsum[i] : 0;
        int orig = x;
        #pragma unroll
        for (int d = 1; d < 64; d <<= 1) {
            int y = __shfl_up(x, d);
            if (lane >= d) x += y;
        }
        if (i < nb) bsum[i] = carry + x - orig;
        carry += __shfl(x, 63);
    }
}

__global__ __launch_bounds__(256) void scan3_kernel(
    int* __restrict__ offs3, int* __restrict__ cursor3,
    const int* __restrict__ bsum3, int n, int total)
{
    int rel = blockIdx.y;
    int* offs = offs3 + (size_t)rel * (n + 1);
    int* cursor = cursor3 + (size_t)rel * n;
    const int* bsum = bsum3 + (size_t)rel * 512;

    int i = blockIdx.x * 256 + threadIdx.x;
    if (i < n) {
        int v = offs[i] + bsum[blockIdx.x];
        offs[i] = v;
        cursor[i] = v;
    }
    if (i == 0 && blockIdx.y < 3) offs[n] = total;
}

// ---------------------------------------------------------------------------
// 3. place edges (col,val packed as uint2) into row-sorted array
// ---------------------------------------------------------------------------
__global__ __launch_bounds__(256) void place_kernel(
    const int* __restrict__ rows, const int* __restrict__ cols,
    const float* __restrict__ vals, int* __restrict__ cursor,
    uint2* __restrict__ ev, int E)
{
    int e = blockIdx.x * 256 + threadIdx.x;
    if (e >= E) return;
    int pos = atomicAdd(&cursor[rows[e]], 1);
    ev[pos] = make_uint2((unsigned)cols[e], __float_as_uint(vals[e]));
}

// ---------------------------------------------------------------------------
// 4. per-row gather-accumulate into X (bf16):
//    first: X[row] = bf16(h_all[row] + sum val*hr[col])
//    else : X[row] = bf16(X[row]     + sum val*hr[col])
//    one wave per row, lane holds features (2*lane, 2*lane+1).
//    2-deep software pipeline on the gathers.
// ---------------------------------------------------------------------------
__global__ __launch_bounds__(256) void accum_kernel(
    const unsigned short* __restrict__ hr, const int* __restrict__ offs,
    const uint2* __restrict__ ev, const float* __restrict__ h_item,
    const float* __restrict__ h_user, unsigned short* __restrict__ X,
    int N, int Ni, int first)
{
    int row = blockIdx.x * 4 + (threadIdx.x >> 6);
    if (row >= N) return;
    int lane = threadIdx.x & 63;
    int s = offs[row], t = offs[row + 1];

    float a0, a1;
    if (first) {
        const float* hsrc = (row < Ni) ? h_item + (size_t)row * D
                                       : h_user + (size_t)(row - Ni) * D;
        float2 hv = *reinterpret_cast<const float2*>(hsrc + lane * 2);
        a0 = hv.x; a1 = hv.y;
    } else {
        if (s == t) return;                       // nothing to add this relation
        ushort2 xv = *reinterpret_cast<const ushort2*>(X + (size_t)row * D + lane * 2);
        a0 = bf2f(xv.x); a1 = bf2f(xv.y);
    }

    uint2 e = make_uint2(0u, 0u);
    ushort2 g = make_ushort2(0, 0);
    if (s < t) {
        e = ev[s];
        g = *reinterpret_cast<const ushort2*>(hr + ((size_t)e.x << 7) + lane * 2);
    }
    for (int p = s; p < t; ++p) {
        uint2 en = e; ushort2 gn = g;
        if (p + 1 < t) {
            en = ev[p + 1];
            gn = *reinterpret_cast<const ushort2*>(hr + ((size_t)en.x << 7) + lane * 2);
        }
        float v = __uint_as_float(e.y);
        a0 = fmaf(v, bf2f(g.x), a0);
        a1 = fmaf(v, bf2f(g.y), a1);
        e = en; g = gn;
    }
    *reinterpret_cast<ushort2*>(X + (size_t)row * D + lane * 2) =
        make_ushort2(f2bf(a0), f2bf(a1));
}

// ---------------------------------------------------------------------------
// MFMA GEMM, M x 128 @ (128x128)^T, K = 128. 128-row tile, 4 waves (2x2),
// per wave 64x64 out = 4x4 frags of 16x16, K in 4 steps of 32.
// LDS rows stride 272 B -> conflict-free ds_read_b128.
// AMODE 0: A = concat(h_item,h_user) f32 -> bf16 on stage (guard row < Ntot).
// AMODE 1: A = bf16 X (pre-offset base pointer).
// FINAL 0: out = bf16 tile (hr), unguarded (M padded to 128).
// FINAL 1: out = f32 with bias+relu, guarded row < Mvalid.
// ---------------------------------------------------------------------------
template<int AMODE, int FINAL>
__global__ __launch_bounds__(256) void gemm128(
    const void* __restrict__ Aptr, const void* __restrict__ A2ptr,
    const float* __restrict__ Wf, const float* __restrict__ biasp,
    void* __restrict__ outp, int Ni, int Ntot, int Mvalid)
{
    __shared__ char LDS[2 * 128 * 272];          // 69632 B
    char* As = LDS;
    char* Bs = LDS + 128 * 272;
    const int tid  = threadIdx.x;
    const int lane = tid & 63;
    const int wv   = tid >> 6;
    const int row0 = blockIdx.x * 128;

    // ---- stage B: W (f32 row-major [n][k]) -> bf16 LDS
    #pragma unroll
    for (int i = 0; i < 8; ++i) {
        int idx = i * 256 + tid;
        int r = idx >> 4, u = idx & 15;
        const float* wp = Wf + r * D + u * 8;
        float4 w0 = *reinterpret_cast<const float4*>(wp);
        float4 w1 = *reinterpret_cast<const float4*>(wp + 4);
        u8x16_t us;
        us[0]=f2bf(w0.x); us[1]=f2bf(w0.y); us[2]=f2bf(w0.z); us[3]=f2bf(w0.w);
        us[4]=f2bf(w1.x); us[5]=f2bf(w1.y); us[6]=f2bf(w1.z); us[7]=f2bf(w1.w);
        *reinterpret_cast<u8x16_t*>(&Bs[r * 272 + u * 16]) = us;
    }
    // ---- stage A
    #pragma unroll
    for (int i = 0; i < 8; ++i) {
        int idx = i * 256 + tid;
        int r = idx >> 4, u = idx & 15;
        int gr = row0 + r;
        u8x16_t us = {};
        if (AMODE == 0) {
            if (gr < Ntot) {
                const float* hp = (gr < Ni)
                    ? (const float*)Aptr  + (size_t)gr * D
                    : (const float*)A2ptr + (size_t)(gr - Ni) * D;
                float4 a0 = *reinterpret_cast<const float4*>(hp + u * 8);
                float4 a1 = *reinterpret_cast<const float4*>(hp + u * 8 + 4);
                us[0]=f2bf(a0.x); us[1]=f2bf(a0.y); us[2]=f2bf(a0.z); us[3]=f2bf(a0.w);
                us[4]=f2bf(a1.x); us[5]=f2bf(a1.y); us[6]=f2bf(a1.z); us[7]=f2bf(a1.w);
            }
        } else {
            us = *reinterpret_cast<const u8x16_t*>(
                (const unsigned short*)Aptr + (size_t)gr * D + u * 8);
        }
        *reinterpret_cast<u8x16_t*>(&As[r * 272 + u * 16]) = us;
    }
    __syncthreads();

    const int wm = wv >> 1, wn = wv & 1;
    f4_t acc[4][4] = {};

    #pragma unroll
    for (int kk = 0; kk < 4; ++kk) {
        const int ku = kk * 4 + (lane >> 4);
        bf8_t a[4], b[4];
        #pragma unroll
        for (int mi = 0; mi < 4; ++mi) {
            int r = wm * 64 + mi * 16 + (lane & 15);
            a[mi] = *reinterpret_cast<const bf8_t*>(&As[r * 272 + ku * 16]);
        }
        #pragma unroll
        for (int nj = 0; nj < 4; ++nj) {
            int r = wn * 64 + nj * 16 + (lane & 15);
            b[nj] = *reinterpret_cast<const bf8_t*>(&Bs[r * 272 + ku * 16]);
        }
        #pragma unroll
        for (int mi = 0; mi < 4; ++mi)
            #pragma unroll
            for (int nj = 0; nj < 4; ++nj)
                acc[mi][nj] = __builtin_amdgcn_mfma_f32_16x16x32_bf16(
                    a[mi], b[nj], acc[mi][nj], 0, 0, 0);
    }
    __syncthreads();

    if (FINAL == 0) {
        // C -> LDS bf16 (stride 272), then coalesced bf16 rows out
        #pragma unroll
        for (int mi = 0; mi < 4; ++mi)
            #pragma unroll
            for (int nj = 0; nj < 4; ++nj)
                #pragma unroll
                for (int q = 0; q < 4; ++q) {
                    int r = wm * 64 + mi * 16 + (lane >> 4) * 4 + q;
                    int c = wn * 64 + nj * 16 + (lane & 15);
                    *reinterpret_cast<unsigned short*>(&As[r * 272 + c * 2]) =
                        f2bf(acc[mi][nj][q]);
                }
        __syncthreads();
        #pragma unroll
        for (int i = 0; i < 8; ++i) {
            int idx = i * 256 + tid;
            int r = idx >> 4, u = idx & 15;
            u8x16_t v = *reinterpret_cast<const u8x16_t*>(&As[r * 272 + u * 16]);
            *reinterpret_cast<u8x16_t*>(
                (unsigned short*)outp + (size_t)(row0 + r) * D + u * 8) = v;
        }
    } else {
        // C -> LDS f32 (stride 544 = 69632/128), bias+relu, guarded f32 rows out
        #pragma unroll
        for (int mi = 0; mi < 4; ++mi)
            #pragma unroll
            for (int nj = 0; nj < 4; ++nj)
                #pragma unroll
                for (int q = 0; q < 4; ++q) {
                    int r = wm * 64 + mi * 16 + (lane >> 4) * 4 + q;
                    int c = wn * 64 + nj * 16 + (lane & 15);
                    *reinterpret_cast<float*>(&LDS[r * 544 + c * 4]) = acc[mi][nj][q];
                }
        __syncthreads();
        #pragma unroll
        for (int i = 0; i < 16; ++i) {
            int idx = i * 256 + tid;
            int r = idx >> 5, u = idx & 31;
            int gr = row0 + r;
            if (gr < Mvalid) {
                f4_t v = *reinterpret_cast<const f4_t*>(&LDS[r * 544 + u * 16]);
                float4 bb = *reinterpret_cast<const float4*>(biasp + u * 4);
                v[0] = fmaxf(v[0] + bb.x, 0.f);
                v[1] = fmaxf(v[1] + bb.y, 0.f);
                v[2] = fmaxf(v[2] + bb.z, 0.f);
                v[3] = fmaxf(v[3] + bb.w, 0.f);
                *reinterpret_cast<f4_t*>((float*)outp + (size_t)gr * D + u * 4) = v;
            }
        }
    }
}

// ---------------------------------------------------------------------------
extern "C" void kernel_launch(void* const* d_in, const int* in_sizes, int n_in,
                              void* d_out, int out_size, void* d_ws, size_t ws_size,
                              hipStream_t stream)
{
    const float* h_item = (const float*)d_in[0];
    const float* h_user = (const float*)d_in[1];
    const float* W_rel  = (const float*)d_in[2];
    const float* W_item = (const float*)d_in[3];
    const float* b_item = (const float*)d_in[4];
    const float* W_user = (const float*)d_in[5];
    const float* b_user = (const float*)d_in[6];
    const float* vals   = (const float*)d_in[7];
    const int*   rows   = (const int*)d_in[8];
    const int*   cols   = (const int*)d_in[9];

    const int Ni = in_sizes[0] / D;          // 80000
    const int Nu = in_sizes[1] / D;          // 20000
    const int N  = Ni + Nu;                  // 100000
    const int NR = in_sizes[2] / (D * D);    // 3
    const int E  = in_sizes[7] / NR;         // 1,600,000
    const int MPAD = ((N + 127) / 128) * 128;    // 100096

    // workspace carve (~67 MB), 256B-aligned regions
    auto align_up = [](size_t x) { return (x + 255) & ~(size_t)255; };
    char* p = (char*)d_ws;
    unsigned short* hr = (unsigned short*)p; p += align_up((size_t)MPAD * D * 2);
    unsigned short* X  = (unsigned short*)p; p += align_up((size_t)MPAD * D * 2);
    uint2* ev          = (uint2*)p;          p += align_up((size_t)E * 8);
    int* count3        = (int*)p;            p += align_up((size_t)3 * N * 4);
    int* offs3         = (int*)p;            p += align_up((size_t)3 * (N + 1) * 4);
    int* cursor3       = (int*)p;            p += align_up((size_t)3 * N * 4);
    int* bsum3         = (int*)p;            p += align_up((size_t)3 * 512 * 4);
    float* out = (float*)d_out;

    const int nb = (N + 255) / 256;          // 391

    // CSR counts for all relations up-front
    hipMemsetAsync(count3, 0, (size_t)3 * N * sizeof(int), stream);
    hist_all_kernel<<<(3 * E + 255) / 256, 256, 0, stream>>>(rows, count3, E, N);
    scan1_kernel<<<dim3(nb, 3), 256, 0, stream>>>(count3, offs3, bsum3, N);
    scan2_kernel<<<3, 64, 0, stream>>>(bsum3, nb);
    scan3_kernel<<<dim3(nb, 3), 256, 0, stream>>>(offs3, cursor3, bsum3, N, E);

    for (int r = 0; r < NR; ++r) {
        place_kernel<<<(E + 255) / 256, 256, 0, stream>>>(
            rows + (size_t)r * E, cols + (size_t)r * E, vals + (size_t)r * E,
            cursor3 + (size_t)r * N, ev, E);

        gemm128<0, 0><<<MPAD / 128, 256, 0, stream>>>(
            h_item, h_user, W_rel + (size_t)r * D * D, nullptr, hr, Ni, N, 0);

        accum_kernel<<<(N + 3) / 4, 256, 0, stream>>>(
            hr, offs3 + (size_t)r * (N + 1), ev, h_item, h_user, X, N, Ni,
            r == 0 ? 1 : 0);
    }

    // out_item = relu(X[:Ni] @ W_item^T + b_item)
    gemm128<1, 1><<<(Ni + 127) / 128, 256, 0, stream>>>(
        X, nullptr, W_item, b_item, out, 0, 0, Ni);
    // out_user = relu(X[Ni:] @ W_user^T + b_user)
    gemm128<1, 1><<<(MPAD - Ni) / 128, 256, 0, stream>>>(
        X + (size_t)Ni * D, nullptr, W_user, b_user, out + (size_t)Ni * D, 0, 0, Nu);
}